// Round 8
// baseline (92.132 us; speedup 1.0000x reference)
//
#include <hip/hip_runtime.h>
#include <math.h>

#define B_ROWS 8192
#define NPROTO 10
#define NCLS   10
#define NPATCH 196
#define WPAD   12                            // class dim padded 10->12 (16B align)

// workspace layout (floats)
#define TABLE_OFF 0                          // 80: per proto [cy0..3, sy0..3]
#define WT2_OFF   128                        // 196*120: [p][proto*12+c]
#define PART_OFF  (128 + NPATCH * NPROTO * WPAD)   // 7*8192*10 partial logits
#define XS_STRIDE 113                        // 113%32=17 -> conflict-free

typedef float v2f __attribute__((ext_vector_type(2)));

// ---------- prep: sincos table + padded weight transpose ----------
__global__ __launch_bounds__(256) void quanv_prep(
    const float* __restrict__ W, const float* __restrict__ protos,
    float* __restrict__ ws) {
  int idx = blockIdx.x * 256 + threadIdx.x;
  if (idx < NPROTO * 8) {
    int proto = idx >> 3, j = idx & 7;
    float h = 0.5f * protos[proto * 4 + (j & 3)];
    ws[TABLE_OFF + idx] = (j < 4) ? __cosf(h) : __sinf(h);
  }
  if (idx < NPATCH * NPROTO * WPAD) {
    int p     = idx / (NPROTO * WPAD);
    int rem   = idx - p * (NPROTO * WPAD);
    int proto = rem / WPAD;
    int c     = rem - proto * WPAD;
    ws[WT2_OFF + idx] =
        (c < NCLS) ? W[c * (NPROTO * NPATCH) + proto * NPATCH + p] : 0.0f;
  }
}

// ---------- main: LDS-staged x AND weights (broadcast ds_read, no s_load misses) ----------
__global__ __launch_bounds__(256) void quanv_main(
    const float* __restrict__ x, const float* __restrict__ ws,
    float* __restrict__ partial) {
  __shared__ float xs[64 * XS_STRIDE];       // 28.9 KB; reused as reduction buffer
  __shared__ float wslab[28 * NPROTO * WPAD];// 13.4 KB: [lp][proto*12+c]
  __shared__ float tbl[80];

  const int tid = threadIdx.x;
  const int bx  = blockIdx.x;                // row group (64 rows)
  const int pr2 = blockIdx.y;                // pair of patch-rows, 0..6
  const int p0  = pr2 * 28;                  // block's first global patch

  // Stage x: 64 rows x 112 floats, coalesced float4.
  {
    const float* src = x + (size_t)bx * 64 * 784 + pr2 * 112;
    for (int i = tid; i < 64 * 28; i += 256) {
      int row = i / 28, quad = i - row * 28;
      float4 v = *(const float4*)(src + (size_t)row * 784 + quad * 4);
      float* d = &xs[row * XS_STRIDE + quad * 4];
      d[0] = v.x; d[1] = v.y; d[2] = v.z; d[3] = v.w;
    }
  }
  // Stage weight slab: 28*120 = 3360 contiguous floats (840 float4), L2-resident.
  {
    const float4* src = (const float4*)(ws + WT2_OFF + p0 * NPROTO * WPAD);
    float4* dst = (float4*)wslab;
    for (int i = tid; i < 840; i += 256) dst[i] = src[i];
  }
  // Stage table: 80 floats.
  if (tid < 20) ((float4*)tbl)[tid] = ((const float4*)(ws + TABLE_OFF))[tid];
  __syncthreads();

  const int wid  = __builtin_amdgcn_readfirstlane(tid >> 6);
  const int lane = tid & 63;                 // lane = row within group
  const float* xr = &xs[lane * XS_STRIDE];

  // Precompute angle sincos for this wave's 7 patches (56 VGPRs)
  v2f cv01[7], cv23[7], sv01[7], sv23[7];
#pragma unroll
  for (int j = 0; j < 7; ++j) {
    int lp  = wid * 7 + j;
    int piL = lp >= 14 ? 1 : 0;
    int pj  = lp - piL * 14;
    int off = piL * 56 + 2 * pj;
    float x0 = xr[off],      x1 = xr[off + 1];
    float x2 = xr[off + 28], x3 = xr[off + 29];
    float s0, c0, s1, c1, s2, c2, s3, c3;
    __sincosf(0.5f * x0, &s0, &c0);
    __sincosf(0.5f * x1, &s1, &c1);
    __sincosf(0.5f * x2, &s2, &c2);
    __sincosf(0.5f * x3, &s3, &c3);
    cv01[j] = (v2f){c0, c1}; cv23[j] = (v2f){c2, c3};
    sv01[j] = (v2f){s0, s1}; sv23[j] = (v2f){s2, s3};
  }

  v2f acc2[5];
#pragma unroll
  for (int k = 0; k < 5; ++k) acc2[k] = (v2f){0.0f, 0.0f};

#pragma unroll
  for (int proto = 0; proto < NPROTO; ++proto) {
    float4 tc = *(const float4*)&tbl[proto * 8];       // broadcast ds_read_b128
    float4 ts = *(const float4*)&tbl[proto * 8 + 4];
    v2f tc01 = {tc.x, tc.y}, tc23 = {tc.z, tc.w};
    v2f ts01 = {ts.x, ts.y}, ts23 = {ts.z, ts.w};
#pragma unroll
    for (int j = 0; j < 7; ++j) {
      v2f t01 = __builtin_elementwise_fma(cv01[j], tc01, sv01[j] * ts01);
      v2f t23 = __builtin_elementwise_fma(cv23[j], tc23, sv23[j] * ts23);
      float q = fabsf((t01.x * t01.y) * (t23.x * t23.y));
      v2f qq = {q, q};
      const float* wq = &wslab[(wid * 7 + j) * (NPROTO * WPAD) + proto * WPAD];
      float4 wA = *(const float4*)(wq);      // broadcast ds_read (uniform addr)
      float4 wB = *(const float4*)(wq + 4);
      float2 wC = *(const float2*)(wq + 8);
      acc2[0] = __builtin_elementwise_fma(qq, (v2f){wA.x, wA.y}, acc2[0]);
      acc2[1] = __builtin_elementwise_fma(qq, (v2f){wA.z, wA.w}, acc2[1]);
      acc2[2] = __builtin_elementwise_fma(qq, (v2f){wB.x, wB.y}, acc2[2]);
      acc2[3] = __builtin_elementwise_fma(qq, (v2f){wB.z, wB.w}, acc2[3]);
      acc2[4] = __builtin_elementwise_fma(qq, (v2f){wC.x, wC.y}, acc2[4]);
    }
  }

  // cross-wave reduction: reuse xs (dead after sincos precompute), stride 11
  __syncthreads();
  {
    float* myred = &xs[(wid * 64 + lane) * 11];
#pragma unroll
    for (int k = 0; k < 5; ++k) {
      myred[2 * k]     = acc2[k].x;
      myred[2 * k + 1] = acc2[k].y;
    }
  }
  __syncthreads();

  for (int i = tid; i < 64 * NCLS; i += 256) {
    int row = i / NCLS, c = i - row * NCLS;
    int o = row * 11 + c;
    float s = xs[o] + xs[704 + o] + xs[1408 + o] + xs[2112 + o];
    partial[((size_t)pr2 * B_ROWS + (size_t)bx * 64 + row) * NCLS + c] = s;
  }
}

// ---------- final: sum 7 partials + bias + log_softmax ----------
__global__ __launch_bounds__(256) void quanv_final(
    const float* __restrict__ partial, const float* __restrict__ bias,
    float* __restrict__ out) {
  int r = blockIdx.x * 256 + threadIdx.x;
  float v[NCLS];
#pragma unroll
  for (int c = 0; c < NCLS; c += 2) {
    float2 bb = *(const float2*)(bias + c);
    v[c] = bb.x; v[c + 1] = bb.y;
  }
  for (int y = 0; y < 7; ++y) {
    const float* pp = partial + ((size_t)y * B_ROWS + r) * NCLS;
#pragma unroll
    for (int c = 0; c < NCLS; c += 2) {
      float2 t = *(const float2*)(pp + c);
      v[c] += t.x; v[c + 1] += t.y;
    }
  }
  float m = v[0];
#pragma unroll
  for (int c = 1; c < NCLS; ++c) m = fmaxf(m, v[c]);
  float sum = 0.0f;
#pragma unroll
  for (int c = 0; c < NCLS; ++c) sum += __expf(v[c] - m);
  float lse = m + __logf(sum);
#pragma unroll
  for (int c = 0; c < NCLS; c += 2) {
    float2 o = {v[c] - lse, v[c + 1] - lse};
    *(float2*)(out + (size_t)r * NCLS + c) = o;
  }
}

extern "C" void kernel_launch(void* const* d_in, const int* in_sizes, int n_in,
                              void* d_out, int out_size, void* d_ws, size_t ws_size,
                              hipStream_t stream) {
  const float* x      = (const float*)d_in[0];
  const float* protos = (const float*)d_in[1];
  const float* W      = (const float*)d_in[2];
  const float* bias   = (const float*)d_in[3];
  float* out = (float*)d_out;
  float* ws  = (float*)d_ws;

  quanv_prep<<<(NPATCH * NPROTO * WPAD + 255) / 256, 256, 0, stream>>>(W, protos, ws);
  quanv_main<<<dim3(B_ROWS / 64, 7), 256, 0, stream>>>(x, ws, ws + PART_OFF);
  quanv_final<<<B_ROWS / 256, 256, 0, stream>>>(ws + PART_OFF, bias, out);
}